// Round 1
// 955.628 us; speedup vs baseline: 3.2256x; 3.2256x over previous
//
#include <hip/hip_runtime.h>
#include <hip/hip_bf16.h>

// Problem constants
#define BB   8
#define EE   16384

typedef __attribute__((ext_vector_type(8))) short short8;
typedef __attribute__((ext_vector_type(4))) float float4v;

__device__ __forceinline__ float bf2f(unsigned short u) {
    unsigned int x = ((unsigned int)u) << 16;
    return __uint_as_float(x);
}
__device__ __forceinline__ unsigned short f2bf(float f) {
    unsigned int x = __float_as_uint(f);
    unsigned int r = (x + 0x7fffu + ((x >> 16) & 1u)) >> 16;  // RNE
    return (unsigned short)r;
}

// pack two f32 -> bf16 pair (round-half-up; <=1ulp from RNE, fine at this tol)
__device__ __forceinline__ unsigned int pack2(float lo, float hi) {
    return ((__float_as_uint(lo) + 0x8000u) >> 16) |
           ((__float_as_uint(hi) + 0x8000u) & 0xffff0000u);
}
__device__ __forceinline__ unsigned int tap_add_w(unsigned int a, unsigned int b) {
    float al = __uint_as_float(a << 16);
    float ah = __uint_as_float(a & 0xffff0000u);
    float bl = __uint_as_float(b << 16);
    float bh = __uint_as_float(b & 0xffff0000u);
    return pack2(al + bl, ah + bh);
}
__device__ __forceinline__ unsigned int tap_ad_w(unsigned int a, unsigned int b) {
    float al = __uint_as_float(a << 16);
    float ah = __uint_as_float(a & 0xffff0000u);
    float bl = __uint_as_float(b << 16);
    float bh = __uint_as_float(b & 0xffff0000u);
    return pack2(fabsf(al - bl), fabsf(ah - bh));
}
__device__ __forceinline__ uint4 tap_add_v(uint4 a, uint4 b) {
    return make_uint4(tap_add_w(a.x, b.x), tap_add_w(a.y, b.y),
                      tap_add_w(a.z, b.z), tap_add_w(a.w, b.w));
}
__device__ __forceinline__ uint4 tap_ad_v(uint4 a, uint4 b) {
    return make_uint4(tap_ad_w(a.x, b.x), tap_ad_w(a.y, b.y),
                      tap_ad_w(a.z, b.z), tap_ad_w(a.w, b.w));
}

// ---------------------------------------------------------------------------
// Transpose [B,C,E] f32 -> [B,E,C] bf16. grid = B * (E/64) * (C/128), 256 thr.
// ---------------------------------------------------------------------------
template<int C>
__global__ __launch_bounds__(256) void transpose_in(
    const float* __restrict__ src, unsigned short* __restrict__ dst)
{
    __shared__ float tile[128][65];
    const int nbe = EE / 64;  // 256
    int bid  = blockIdx.x;
    int b    = bid / (nbe * (C / 128));
    int rem  = bid % (nbe * (C / 128));
    int cblk = rem / nbe;
    int e0   = (rem % nbe) * 64;
    int c0   = cblk * 128;
    int t = threadIdx.x;
    {
        int e = t & 63, cb = t >> 6;
        for (int c = cb; c < 128; c += 4)
            tile[c][e] = src[((size_t)b * C + c0 + c) * EE + e0 + e];
    }
    __syncthreads();
    {
        int c = t & 127, eb = t >> 7;
        for (int ee = eb; ee < 64; ee += 2)
            dst[((size_t)b * EE + e0 + ee) * C + c0 + c] = f2bf(tile[c][ee]);
    }
}

// ---------------------------------------------------------------------------
// Weight -> MFMA B-fragment layout, bf16.
// Bf[((kt*16 + nt)*64 + lane)*8 + j] = W[o=nt*16+(lane&15)][c][tap]
// with k = kt*32 + (lane>>4)*8 + j ; ci=k/320; r=k%320; tap=r>>6; c=ci*64+(r&63).
// grid = 5*C blocks of 256 (one elem per thread).
// ---------------------------------------------------------------------------
template<int C>
__global__ __launch_bounds__(256) void wtf_kernel(
    const float* __restrict__ W, unsigned short* __restrict__ Bf)
{
    int idx  = blockIdx.x * 256 + threadIdx.x;
    int j    = idx & 7;
    int lane = (idx >> 3) & 63;
    int nt   = (idx >> 9) & 15;
    int kt   = idx >> 13;
    int o = nt * 16 + (lane & 15);
    int k = kt * 32 + (lane >> 4) * 8 + j;
    int ci = k / 320;
    int r  = k % 320;
    int tap = r >> 6;
    int c   = ci * 64 + (r & 63);
    Bf[idx] = f2bf(W[((size_t)o * C + c) * 5 + tap]);
}

// ---------------------------------------------------------------------------
// MFMA mesh conv. A1/A2 bf16 edge-major (dual-source concat: [0,C1) from A1,
// [C1,C1+C2) from A2). Bfrag = weights in fragment layout. Out bf16 [B,E,256].
// Block: 256 thr, 4 waves; wave wv computes ALL 64 edges x outputs
// [wv*64, wv*64+64) -> 4x fewer B-fragment loads than edge-split (each bf
// reused across 4 edge-group MFMAs; B traffic 10.5GB -> 2.6GB per dispatch).
// K chunked: 64 channels x 5 taps = 320 k-elems per chunk, staged in LDS.
// Gather staging is software-pipelined: chunk ci+1's 10 global loads are
// issued into registers before chunk ci's MFMA phase (latency hides under
// MFMA + B loads); regs are committed (taps -> LDS) after the end barrier.
// ---------------------------------------------------------------------------
template<int C1, int C2>
__global__ __launch_bounds__(256, 3) void conv_mfma(
    const unsigned short* __restrict__ A1,
    const unsigned short* __restrict__ A2,
    const int* __restrict__ ei,
    const unsigned short* __restrict__ Bfrag,
    const float* __restrict__ bias,
    unsigned short* __restrict__ out)
{
    constexpr int C    = C1 + C2;
    constexpr int NCH  = C / 64;
    constexpr int ROWE = 5 * 64 + 8;  // 328 elems; +8 pad -> conflict-free b128

    __shared__ unsigned short Alds[64 * ROWE];  // 41 KB
    __shared__ int nbr[64][4];

    const int tid = threadIdx.x;
    const int b   = blockIdx.x >> 8;          // 256 blocks per batch
    const int e0  = (blockIdx.x & 255) * 64;

    ((int*)nbr)[tid] = ei[((size_t)b * EE + e0) * 4 + tid];

    const int lane = tid & 63;
    const int wv   = tid >> 6;     // wave -> nt slice [wv*4, wv*4+4)
    const int col  = lane & 15;
    const int quad = lane >> 4;

    float4v acc[4][4];             // [edge-group][nt-local]
#pragma unroll
    for (int ntl = 0; ntl < 4; ntl++) {
        float bv = bias[(wv * 4 + ntl) * 16 + col];
        float4v v = {bv, bv, bv, bv};
#pragma unroll
        for (int eg2 = 0; eg2 < 4; eg2++) acc[eg2][ntl] = v;
    }
    __syncthreads();

    const int eg = tid >> 2;   // staging edge 0..63
    const int g  = tid & 3;    // 16-channel group
    // hoist neighbor ids to registers (constant across chunks)
    const int nA = nbr[eg][0], nB = nbr[eg][1], nC = nbr[eg][2], nD = nbr[eg][3];
    const int es = e0 + eg;

    // prefetch registers for one chunk of gather staging (10 x uint4 = 40 VGPR)
    uint4 s0a, s0b, r1a, r1b, r2a, r2b, r3a, r3b, r4a, r4b;

    auto issue = [&](int ci) {
        const int c0 = ci * 64;
        const unsigned short* S = A1 + (size_t)b * EE * C1;
        int stride = C1, cc = c0;
        if constexpr (C2 > 0) {
            if (c0 >= C1) { S = A2 + (size_t)b * EE * C2; stride = C2; cc = c0 - C1; }
        }
        const int cho = cc + g * 16;
        const unsigned short* p0 = S + (size_t)es * stride + cho;
        const unsigned short* p1 = S + (size_t)nA * stride + cho;
        const unsigned short* p2 = S + (size_t)nB * stride + cho;
        const unsigned short* p3 = S + (size_t)nC * stride + cho;
        const unsigned short* p4 = S + (size_t)nD * stride + cho;
        s0a = *(const uint4*)p0; s0b = *(const uint4*)(p0 + 8);
        r1a = *(const uint4*)p1; r1b = *(const uint4*)(p1 + 8);
        r2a = *(const uint4*)p2; r2b = *(const uint4*)(p2 + 8);
        r3a = *(const uint4*)p3; r3b = *(const uint4*)(p3 + 8);
        r4a = *(const uint4*)p4; r4b = *(const uint4*)(p4 + 8);
    };

    issue(0);

    for (int ci = 0; ci < NCH; ci++) {
        // commit staged registers -> taps -> LDS
        {
            unsigned short* row = &Alds[eg * ROWE + g * 16];
            *(uint4*)(row)           = s0a;
            *(uint4*)(row + 8)       = s0b;
            *(uint4*)(row + 64)      = tap_add_v(r1a, r3a);
            *(uint4*)(row + 64 + 8)  = tap_add_v(r1b, r3b);
            *(uint4*)(row + 128)     = tap_add_v(r2a, r4a);
            *(uint4*)(row + 128 + 8) = tap_add_v(r2b, r4b);
            *(uint4*)(row + 192)     = tap_ad_v(r1a, r3a);
            *(uint4*)(row + 192 + 8) = tap_ad_v(r1b, r3b);
            *(uint4*)(row + 256)     = tap_ad_v(r2a, r4a);
            *(uint4*)(row + 256 + 8) = tap_ad_v(r2b, r4b);
        }
        __syncthreads();

        if (ci + 1 < NCH) issue(ci + 1);   // loads fly during MFMA phase

        const short8* B8 = (const short8*)Bfrag + (size_t)(ci * 10) * 1024 + lane;
        const unsigned short* abase = &Alds[col * ROWE + quad * 8];
#pragma unroll
        for (int ks = 0; ks < 10; ks++) {
            short8 bf0 = B8[ks * 1024 + (wv * 4 + 0) * 64];
            short8 bf1 = B8[ks * 1024 + (wv * 4 + 1) * 64];
            short8 bf2 = B8[ks * 1024 + (wv * 4 + 2) * 64];
            short8 bf3 = B8[ks * 1024 + (wv * 4 + 3) * 64];
#pragma unroll
            for (int eg2 = 0; eg2 < 4; eg2++) {
                short8 af = *(const short8*)(abase + eg2 * 16 * ROWE + ks * 32);
                acc[eg2][0] = __builtin_amdgcn_mfma_f32_16x16x32_bf16(af, bf0, acc[eg2][0], 0, 0, 0);
                acc[eg2][1] = __builtin_amdgcn_mfma_f32_16x16x32_bf16(af, bf1, acc[eg2][1], 0, 0, 0);
                acc[eg2][2] = __builtin_amdgcn_mfma_f32_16x16x32_bf16(af, bf2, acc[eg2][2], 0, 0, 0);
                acc[eg2][3] = __builtin_amdgcn_mfma_f32_16x16x32_bf16(af, bf3, acc[eg2][3], 0, 0, 0);
            }
        }
        if (ci + 1 < NCH) __syncthreads();  // protect Alds before next commit
    }

    // epilogue: C/D layout col=lane&15 (=n within tile), row=quad*4+reg (=edge)
#pragma unroll
    for (int eg2 = 0; eg2 < 4; eg2++) {
        unsigned short* ob = out + ((size_t)b * EE + e0 + eg2 * 16 + quad * 4) * 256 + col;
#pragma unroll
        for (int ntl = 0; ntl < 4; ntl++) {
#pragma unroll
            for (int r = 0; r < 4; r++)
                ob[(size_t)r * 256 + (wv * 4 + ntl) * 16] = f2bf(acc[eg2][ntl][r]);
        }
    }
}

// ---------------------------------------------------------------------------
// Stats (no atomics): Y bf16 [B,E,256] -> partials[blk][{sum,sumsq}][o]
// grid = B*(E/256) = 512 blocks, 256 threads (t = channel o).
// ---------------------------------------------------------------------------
__global__ __launch_bounds__(256) void stats_kernel(
    const unsigned short* __restrict__ Y, float* __restrict__ partials)
{
    const int nbe = EE / 256;  // 64
    int blk = blockIdx.x;
    int b   = blk / nbe;
    int e0  = (blk % nbe) * 256;
    int o   = threadIdx.x;
    float s = 0.f, s2 = 0.f;
    const unsigned short* p = Y + ((size_t)b * EE + e0) * 256 + o;
    for (int i = 0; i < 256; i++) {
        float v = bf2f(p[(size_t)i * 256]);
        s += v;
        s2 += v * v;
    }
    partials[(size_t)blk * 512 + o]       = s;
    partials[(size_t)blk * 512 + 256 + o] = s2;
}

// grid = B blocks of 256; thread (b,o) reduces 64 partial blocks.
__global__ __launch_bounds__(256) void finalize_kernel(
    const float* __restrict__ partials, float* __restrict__ mr)
{
    int b = blockIdx.x, o = threadIdx.x;
    float s = 0.f, s2 = 0.f;
    for (int j = 0; j < 64; j++) {
        s  += partials[(size_t)(b * 64 + j) * 512 + o];
        s2 += partials[(size_t)(b * 64 + j) * 512 + 256 + o];
    }
    const float invE = 1.0f / (float)EE;
    float m = s * invE;
    float v = s2 * invE - m * m;
    v = fmaxf(v, 0.f);
    mr[b * 256 + o] = m;
    mr[2048 + b * 256 + o] = rsqrtf(v + 1e-5f);
}

// ---------------------------------------------------------------------------
// Apply: Xout = relu((Y - mean)*rstd [+ Xres]), bf16 in/out, edge-major.
// ---------------------------------------------------------------------------
template<bool RES>
__global__ __launch_bounds__(256) void apply_kernel(
    const unsigned short* __restrict__ Y,
    const unsigned short* __restrict__ Xres,
    const float* __restrict__ mr,
    unsigned short* __restrict__ Xout)
{
    size_t idx = (size_t)blockIdx.x * 256 + threadIdx.x;
    int o = (int)(idx & 255);
    size_t be = idx >> 8;
    int b = (int)(be >> 14);  // / E
    float v = (bf2f(Y[idx]) - mr[b * 256 + o]) * mr[2048 + b * 256 + o];
    if (RES) v += bf2f(Xres[idx]);
    v = fmaxf(v, 0.f);
    Xout[idx] = f2bf(v);
}

// ---------------------------------------------------------------------------
// Final apply + transpose: out[b][o][e] = relu(norm(Y)+Xres), FLOAT32 output.
// grid = B*(E/32) = 4096 blocks, 256 threads. LDS tile float[256][33] = 33 KB.
// ---------------------------------------------------------------------------
__global__ __launch_bounds__(256) void apply_final_kernel(
    const unsigned short* __restrict__ Y,
    const unsigned short* __restrict__ Xres,
    const float* __restrict__ mr,
    float* __restrict__ out)
{
    __shared__ float tile[256][33];
    const int nbe = EE / 32;  // 512
    int b  = blockIdx.x / nbe;
    int e0 = (blockIdx.x % nbe) * 32;
    int t = threadIdx.x;
    {
        int o = t;
        float m = mr[b * 256 + o], r = mr[2048 + b * 256 + o];
        const unsigned short* yp = Y + ((size_t)b * EE + e0) * 256 + o;
        const unsigned short* xp = Xres + ((size_t)b * EE + e0) * 256 + o;
        for (int e = 0; e < 32; e++) {
            float v = (bf2f(yp[(size_t)e * 256]) - m) * r + bf2f(xp[(size_t)e * 256]);
            tile[o][e] = fmaxf(v, 0.f);
        }
    }
    __syncthreads();
    {
        int e = t & 31, ob = t >> 5;
        for (int o = ob; o < 256; o += 8)
            out[((size_t)b * 256 + o) * EE + e0 + e] = tile[o][e];
    }
}

// ---------------------------------------------------------------------------
extern "C" void kernel_launch(void* const* d_in, const int* in_sizes, int n_in,
                              void* d_out, int out_size, void* d_ws, size_t ws_size,
                              hipStream_t stream)
{
    const float* from_up   = (const float*)d_in[0];
    const float* from_down = (const float*)d_in[1];
    const int*   ei        = (const int*)d_in[2];
    const float* W_up = (const float*)d_in[3];
    const float* b_up = (const float*)d_in[4];
    const float* W1   = (const float*)d_in[5];
    const float* b1   = (const float*)d_in[6];
    const float* W2a  = (const float*)d_in[7];
    const float* b2a  = (const float*)d_in[8];
    const float* W2b  = (const float*)d_in[9];
    const float* b2b  = (const float*)d_in[10];
    float* out = (float*)d_out;

    char* ws = (char*)d_ws;
    const size_t MB = 1048576;
    // aux @ [0, 8 MiB): bf16 B-fragments + f32 partials/mr
    unsigned short* Wt_up = (unsigned short*)(ws + 0);         //   327,680 B
    unsigned short* Wt1   = (unsigned short*)(ws + 327680);    // 1,310,720 B
    unsigned short* Wt2a  = (unsigned short*)(ws + 1638400);   //   655,360 B
    unsigned short* Wt2b  = (unsigned short*)(ws + 2293760);   //   655,360 B
    float* partials       = (float*)(ws + 2949120);            // 1,048,576 B
    float* mr             = (float*)(ws + 2949120 + 1048576);  //    16,384 B
    // bf16 activation buffers:
    //   A0  @ [8, 40)  MiB : from_up^T   (dead after conv0)
    //   Adn @ [40,104) MiB : from_down^T (dead after conv1)
    //   WA  @ [8, 72)  MiB : X1n, later Y3
    //   WB  @ [72,136) MiB : X2n
    // d_out doubles as two bf16 scratch halves until its final f32 overwrite:
    //   D1 = out bytes [0,64) MiB : C0, later Y2 ; D2 = bytes [64,128) : Y1
    unsigned short* A0  = (unsigned short*)(ws + 8 * MB);
    unsigned short* Adn = (unsigned short*)(ws + 40 * MB);
    unsigned short* WA  = (unsigned short*)(ws + 8 * MB);
    unsigned short* WB  = (unsigned short*)(ws + 72 * MB);
    unsigned short* D1  = (unsigned short*)d_out;
    unsigned short* D2  = (unsigned short*)((char*)d_out + 64 * MB);

    // Weight -> B-fragment transforms (tiny)
    wtf_kernel<128><<<640,  256, 0, stream>>>(W_up, Wt_up);
    wtf_kernel<512><<<2560, 256, 0, stream>>>(W1,   Wt1);
    wtf_kernel<256><<<1280, 256, 0, stream>>>(W2a,  Wt2a);
    wtf_kernel<256><<<1280, 256, 0, stream>>>(W2b,  Wt2b);

    // Input transposes f32 -> bf16 edge-major
    transpose_in<128><<<BB * 256 * 1, 256, 0, stream>>>(from_up, A0);
    transpose_in<256><<<BB * 256 * 2, 256, 0, stream>>>(from_down, Adn);

    const int conv_grid = BB * (EE / 64);  // 2048

    // conv0: A0 -> C0 (D1)
    conv_mfma<128, 0><<<conv_grid, 256, 0, stream>>>(A0, nullptr, ei, Wt_up, b_up, D1);
    // conv1 (concat[C0, Adn]) -> Y1 (D2)
    conv_mfma<256, 256><<<conv_grid, 256, 0, stream>>>(D1, Adn, ei, Wt1, b1, D2);

    // norm1 -> X1n (WA)
    stats_kernel<<<BB * 64, 256, 0, stream>>>(D2, partials);
    finalize_kernel<<<BB, 256, 0, stream>>>(partials, mr);
    apply_kernel<false><<<131072, 256, 0, stream>>>(D2, nullptr, mr, WA);

    // conv2a: X1n -> Y2 (D1); x2 = relu(norm(Y2) + X1n) -> X2n (WB)
    conv_mfma<256, 0><<<conv_grid, 256, 0, stream>>>(WA, nullptr, ei, Wt2a, b2a, D1);
    stats_kernel<<<BB * 64, 256, 0, stream>>>(D1, partials);
    finalize_kernel<<<BB, 256, 0, stream>>>(partials, mr);
    apply_kernel<true><<<131072, 256, 0, stream>>>(D1, WA, mr, WB);

    // conv2b: X2n -> Y3 (WA); out = relu(norm(Y3) + X2n) -> d_out f32 [B,256,E]
    conv_mfma<256, 0><<<conv_grid, 256, 0, stream>>>(WB, nullptr, ei, Wt2b, b2b, WA);
    stats_kernel<<<BB * 64, 256, 0, stream>>>(WA, partials);
    finalize_kernel<<<BB, 256, 0, stream>>>(partials, mr);
    apply_final_kernel<<<BB * (EE / 32), 256, 0, stream>>>(WA, WB, mr, out);
}